// Round 17
// baseline (710.360 us; speedup 1.0000x reference)
//
#include <hip/hip_runtime.h>
#include <hip/hip_bf16.h>

#define NN 100000
#define NE 1600000
#define DD 128
#define FF 256
#define NSTRIPE 16
#define NTILE 6250   // NN / 16 exactly
static constexpr float EPS_ = 1e-5f;

typedef __bf16 bf16x4 __attribute__((ext_vector_type(4)));
typedef __bf16 bf16x8 __attribute__((ext_vector_type(8)));
typedef float  f32x4  __attribute__((ext_vector_type(4)));

__device__ inline float bflo(unsigned int u) { return __uint_as_float(u << 16); }
__device__ inline float bfhi(unsigned int u) { return __uint_as_float(u & 0xFFFF0000u); }

__device__ inline unsigned pack_bf16x2(float x, float y) {
    __hip_bfloat162 t;
    t.x = __float2bfloat16(x);
    t.y = __float2bfloat16(y);
    return *reinterpret_cast<unsigned*>(&t);
}
__device__ inline void bf8_to_f(uint4 u, float* f) {
    f[0] = bflo(u.x); f[1] = bfhi(u.x);
    f[2] = bflo(u.y); f[3] = bfhi(u.y);
    f[4] = bflo(u.z); f[5] = bfhi(u.z);
    f[6] = bflo(u.w); f[7] = bfhi(u.w);
}
__device__ inline uint4 f_to_bf8(const float* f) {
    uint4 u;
    u.x = pack_bf16x2(f[0], f[1]);
    u.y = pack_bf16x2(f[2], f[3]);
    u.z = pack_bf16x2(f[4], f[5]);
    u.w = pack_bf16x2(f[6], f[7]);
    return u;
}
__device__ inline float2 ntload2(const float* p) {
    double d = __builtin_nontemporal_load((const double*)p);
    return *reinterpret_cast<float2*>(&d);
}
__device__ inline float stripe_sum(const float* s, int idx) {
    float r = 0.f;
#pragma unroll
    for (int st = 0; st < NSTRIPE; ++st) r += s[st * 256 + idx];
    return r;
}

// ---------------- init: zero deg/stripes + cvt weights ----------------
__global__ __launch_bounds__(256) void k_init(const float* __restrict__ W,
                                              const float* __restrict__ W1,
                                              const float* __restrict__ W2,
                                              __bf16* __restrict__ Wb,
                                              __bf16* __restrict__ W1b,
                                              __bf16* __restrict__ W2b,
                                              int* __restrict__ deg,
                                              float* __restrict__ stripes) {
    int i = blockIdx.x * 256 + threadIdx.x;
    if (i < NN) deg[i] = 0;
    if (i < 3 * NSTRIPE * 256) stripes[i] = 0.f;
    if (i < 16384) Wb[i] = (__bf16)W[i];
    if (i < 32768) W1b[i] = (__bf16)W1[i];
    if (i < 32768) W2b[i] = (__bf16)W2[i];
}

// ---------------- h = x @ W^T -> bf16, via MFMA; also emits xb = bf16(x) ----------------
__global__ __launch_bounds__(256) void k_gemmx(const float* __restrict__ x,
                                               const __bf16* __restrict__ Wb,
                                               __bf16* __restrict__ h2,
                                               __bf16* __restrict__ xb) {
    __shared__ __bf16 xs[64 * 128];
    int tid = threadIdx.x;
    int row0 = blockIdx.x * 64;
    int V = NN - row0; if (V > 64) V = 64;

    {
        int c0 = (tid & 31) * 4;
        for (int j = 0; j < 8; ++j) {
            int idx = j * 256 + tid;
            int r = idx >> 5;
            float4 v = make_float4(0.f, 0.f, 0.f, 0.f);
            if (r < V) v = ((const float4*)(x + (size_t)row0 * DD))[idx];
            bf16x4 bv; bv[0] = (__bf16)v.x; bv[1] = (__bf16)v.y; bv[2] = (__bf16)v.z; bv[3] = (__bf16)v.w;
            int sw = (((c0 >> 3) ^ (r & 7)) << 3) + (c0 & 7);
            *reinterpret_cast<bf16x4*>(&xs[r * 128 + sw]) = bv;
            if (r < V)   // bf16 copy of x for k_y1 (coalesced 8B stores)
                *reinterpret_cast<bf16x4*>(&xb[(size_t)(row0 + r) * DD + c0]) = bv;
        }
    }
    __syncthreads();

    int l = tid & 63, w = tid >> 6;
    int m0 = w * 16, lr = l & 15, lk = (l >> 4) * 8;
    int mrow = m0 + lr;

    bf16x8 a[4];
    for (int kk = 0; kk < 4; ++kk) {
        int k = kk * 32 + lk;
        int sw = ((k >> 3) ^ (mrow & 7)) << 3;
        a[kk] = *reinterpret_cast<const bf16x8*>(&xs[mrow * 128 + sw]);
    }
    for (int nt = 0; nt < 8; ++nt) {
        int n0 = nt * 16;
        f32x4 acc = {0.f, 0.f, 0.f, 0.f};
        for (int kk = 0; kk < 4; ++kk) {
            bf16x8 b = *reinterpret_cast<const bf16x8*>(&Wb[(n0 + lr) * 128 + kk * 32 + lk]);
            acc = __builtin_amdgcn_mfma_f32_16x16x32_bf16(a[kk], b, acc, 0, 0, 0);
        }
        int n = n0 + lr;
#pragma unroll
        for (int r = 0; r < 4; ++r) {
            int m = m0 + (l >> 4) * 4 + r;
            xs[m * 128 + n] = (__bf16)acc[r];
        }
    }
    for (int i = 0; i < 8; ++i) {
        int j = i * 64 + l;
        int rl = j >> 5;
        int c4 = j & 31;
        int m = m0 + rl;
        if (row0 + m < NN) {
            bf16x4 v = *reinterpret_cast<const bf16x4*>(&xs[m * 128 + c4 * 4]);
            *reinterpret_cast<bf16x4*>(&h2[(size_t)(row0 + m) * 128 + c4 * 4]) = v;
        }
    }
}

// ---------------- deg histogram over dst ----------------
__global__ __launch_bounds__(256) void k_hist(const int* __restrict__ ei,
                                              int* __restrict__ deg) {
    int e = blockIdx.x * 256 + threadIdx.x;
    if (e < NE) atomicAdd(&deg[ei[NE + e]], 1);
}

// ---------------- scan stage A ----------------
__global__ __launch_bounds__(256) void k_scanA(const int* __restrict__ p,
                                               int* __restrict__ bsum) {
    __shared__ int red[256];
    int b = blockIdx.x, tid = threadIdx.x;
    int base = b * 1024;
    int s = 0;
    for (int i = tid; i < 1024; i += 256) {
        int idx = base + i;
        s += (idx < NN) ? p[idx] : 0;
    }
    red[tid] = s;
    __syncthreads();
    for (int d = 128; d > 0; d >>= 1) {
        if (tid < d) red[tid] += red[tid + d];
        __syncthreads();
    }
    if (tid == 0) bsum[b] = red[0];
}

// ---------------- scan stage B (+ empty-node stats fixup) ----------------
__global__ __launch_bounds__(256) void k_scanB(int* __restrict__ p,
                                               const int* __restrict__ bsum,
                                               const float* __restrict__ bias,
                                               float* __restrict__ s1) {
    __shared__ int part[256];
    __shared__ int boff_sh;
    int b = blockIdx.x, tid = threadIdx.x;
    if (tid == 0) {
        int s = 0;
        for (int i = 0; i < b; ++i) s += bsum[i];
        boff_sh = s;
    }
    int base = b * 1024 + tid * 4;
    int4 v = make_int4(0, 0, 0, 0);
    bool full = (base + 3 < NN);
    if (full) v = *(const int4*)(p + base);
    else {
        if (base + 0 < NN) v.x = p[base + 0];
        if (base + 1 < NN) v.y = p[base + 1];
        if (base + 2 < NN) v.z = p[base + 2];
        if (base + 3 < NN) v.w = p[base + 3];
    }
    int tsum = v.x + v.y + v.z + v.w;
    part[tid] = tsum;
    __syncthreads();
    for (int d = 1; d < 256; d <<= 1) {
        int add = (tid >= d) ? part[tid - d] : 0;
        __syncthreads();
        part[tid] += add;
        __syncthreads();
    }
    int texcl = part[tid] - tsum + boff_sh;
    int4 o;
    o.x = texcl;
    o.y = texcl + v.x;
    o.z = texcl + v.x + v.y;
    o.w = texcl + v.x + v.y + v.z;
    if (full) *(int4*)(p + base) = o;
    else {
        if (base + 0 < NN) p[base + 0] = o.x;
        if (base + 1 < NN) p[base + 1] = o.y;
        if (base + 2 < NN) p[base + 2] = o.z;
        if (base + 3 < NN) p[base + 3] = o.w;
    }
    int cnt = ((base + 0 < NN && v.x == 0) ? 1 : 0) +
              ((base + 1 < NN && v.y == 0) ? 1 : 0) +
              ((base + 2 < NN && v.z == 0) ? 1 : 0) +
              ((base + 3 < NN && v.w == 0) ? 1 : 0);
    if (cnt > 0) {
        float fc = (float)cnt;
        for (int c = 0; c < 128; ++c) {
            float bv = bias[c];
            atomicAdd(&s1[c], fc * bv);
            atomicAdd(&s1[128 + c], fc * bv * bv);
        }
    }
}

// ---------------- fill pair[pos]={src,e} sorted by dst ----------------
__global__ __launch_bounds__(256) void k_fill(const int* __restrict__ ei,
                                              int* __restrict__ ptr,
                                              int2* __restrict__ pair) {
    int e = blockIdx.x * 256 + threadIdx.x;
    if (e >= NE) return;
    int s = ei[e];
    int d = ei[NE + e];
    int pos = atomicAdd(&ptr[d], 1);
    pair[pos] = make_int2(s, e);
}

// ---------------- gather: edge-stream, readlane broadcast, 8-deep pipeline ----------------
__device__ inline int first_node_ge(const int* __restrict__ ptr, int bound) {
    if (bound <= 0) return 0;
    int a = 0, b = NN;
    while (a < b) { int m = (a + b) >> 1; if (ptr[m] >= bound) b = m; else a = m + 1; }
    return a + 1;
}

__global__ __launch_bounds__(256) void k_gather(const unsigned int* __restrict__ h2u,
                                                const float* __restrict__ ea,
                                                const int2* __restrict__ pair,
                                                const int* __restrict__ ptr,
                                                const float* __restrict__ bias,
                                                unsigned int* __restrict__ aggb,
                                                float* __restrict__ s1) {
    __shared__ float zsum[128], zsq[128];
    int tid = threadIdx.x;
    if (tid < 128) { zsum[tid] = 0.f; zsq[tid] = 0.f; }
    __syncthreads();
    int lane = tid & 63;
    int wid = blockIdx.x * 4 + (tid >> 6);
    int nw = gridDim.x * 4;
    float2 bv = ((const float2*)bias)[lane];
    float sx = 0.f, qx = 0.f, sy = 0.f, qy = 0.f;

    long long lo = (long long)wid * NE / nw;
    long long hi = (long long)(wid + 1) * NE / nw;
    int n0 = first_node_ge(ptr, (int)lo);
    int n1 = (wid == nw - 1) ? NN : first_node_ge(ptr, (int)hi);

    if (n0 < n1) {
        int jbeg = (n0 == 0) ? 0 : ptr[n0 - 1];
        int jend = ptr[n1 - 1];
        if (jbeg < jend) {
            int curn = n0;
            int cend = ptr[curn];
            while (cend == jbeg) { curn++; cend = ptr[curn]; }
            float ax = 0.f, ay = 0.f;
            int nch = (jend - jbeg + 63) >> 6;
            int2 Qc = pair[jbeg + lane];
            int2 Qn = Qc;

            unsigned H0=0,H1=0,H2=0,H3=0,H4=0,H5=0,H6=0,H7=0;
            float2 A0,A1,A2,A3,A4,A5,A6,A7;
            A0=A1=A2=A3=A4=A5=A6=A7=make_float2(0.f,0.f);

#define GISS(HS, AS, Q, SL) { \
            int sn_ = __builtin_amdgcn_readlane((Q).x, (SL)); \
            int en_ = __builtin_amdgcn_readlane((Q).y, (SL)); \
            HS = h2u[(size_t)sn_ * 64 + lane]; \
            AS = ntload2(ea + (size_t)en_ * DD + 2 * lane); }

            if (jbeg + 0 < jend) GISS(H0, A0, Qc, 0)
            if (jbeg + 1 < jend) GISS(H1, A1, Qc, 1)
            if (jbeg + 2 < jend) GISS(H2, A2, Qc, 2)
            if (jbeg + 3 < jend) GISS(H3, A3, Qc, 3)
            if (jbeg + 4 < jend) GISS(H4, A4, Qc, 4)
            if (jbeg + 5 < jend) GISS(H5, A5, Qc, 5)
            if (jbeg + 6 < jend) GISS(H6, A6, Qc, 6)
            if (jbeg + 7 < jend) GISS(H7, A7, Qc, 7)

            for (int c = 0; c < nch; ++c) {
                int cb = jbeg + (c << 6);
                if (c + 1 < nch) Qn = pair[cb + 64 + lane];
#define GSTEP(S, HS, AS) { \
                int je_ = cb + k + S; \
                if (je_ < jend) { \
                    ax += fmaxf(bflo(HS) + AS.x, 0.f); \
                    ay += fmaxf(bfhi(HS) + AS.y, 0.f); \
                    int je1_ = je_ + 1; \
                    if (je1_ == cend) { \
                        float fx_ = ax + bv.x, fy_ = ay + bv.y; \
                        aggb[(size_t)curn * 64 + lane] = pack_bf16x2(fx_, fy_); \
                        sx += fx_; qx += fx_ * fx_; sy += fy_; qy += fy_ * fy_; \
                        ax = 0.f; ay = 0.f; \
                        curn++; \
                        while (curn < n1 && ptr[curn] == je1_) curn++; \
                        cend = (curn < n1) ? ptr[curn] : -1; \
                    } \
                    int kn_ = k + S + 8; \
                    int jn_ = cb + kn_; \
                    if (jn_ < jend) { \
                        if (kn_ < 64) { GISS(HS, AS, Qc, kn_) } \
                        else { GISS(HS, AS, Qn, kn_ - 64) } \
                    } \
                } }
                for (int k = 0; k < 64; k += 8) {
                    GSTEP(0,H0,A0) GSTEP(1,H1,A1) GSTEP(2,H2,A2) GSTEP(3,H3,A3)
                    GSTEP(4,H4,A4) GSTEP(5,H5,A5) GSTEP(6,H6,A6) GSTEP(7,H7,A7)
                }
                Qc = Qn;
#undef GSTEP
            }
#undef GISS
        }
        // empty-node sweep: write bias into aggb for nodes with no edges
        // (stats contribution handled by k_scanB's fixup)
        unsigned bpk = pack_bf16x2(bv.x, bv.y);
        int prev = (n0 == 0) ? 0 : ptr[n0 - 1];
        for (int i = n0; i < n1; ++i) {
            int end = ptr[i];
            if (end == prev) aggb[(size_t)i * 64 + lane] = bpk;
            prev = end;
        }
    }

    atomicAdd(&zsum[2 * lane], sx);     atomicAdd(&zsq[2 * lane], qx);
    atomicAdd(&zsum[2 * lane + 1], sy); atomicAdd(&zsq[2 * lane + 1], qy);
    __syncthreads();
    int st = (blockIdx.x & (NSTRIPE - 1)) * 256;
    if (tid < 128) {
        atomicAdd(&s1[st + tid], zsum[tid]);
        atomicAdd(&s1[st + 128 + tid], zsq[tid]);
    }
}

// ---------------- y1 = x + relu(bn1(agg)) -> bf16; striped s2 (x read as bf16) ----------------
__global__ __launch_bounds__(256) void k_y1(const uint4* __restrict__ xb4,
                                            const uint4* __restrict__ aggb,
                                            const float* __restrict__ s1,
                                            const float* __restrict__ g,
                                            const float* __restrict__ bb,
                                            uint4* __restrict__ y1b,
                                            float* __restrict__ s2) {
    __shared__ float zs[128], zq[128];
    int tid = threadIdx.x;
    if (tid < 128) { zs[tid] = 0.f; zq[tid] = 0.f; }
    __syncthreads();
    int c0 = (tid & 15) * 8;
    float A[8], C[8], ls[8] = {0,0,0,0,0,0,0,0}, lq[8] = {0,0,0,0,0,0,0,0};
#pragma unroll
    for (int j = 0; j < 8; ++j) {
        int c = c0 + j;
        float m = stripe_sum(s1, c) * (1.f / NN);
        float v = stripe_sum(s1, 128 + c) * (1.f / NN) - m * m;
        float inv = rsqrtf(v + EPS_);
        A[j] = inv * g[c];
        C[j] = bb[c] - m * inv * g[c];
    }
    int step = gridDim.x * 256;
    for (int i = blockIdx.x * 256 + tid; i < NN * 16; i += step) {
        float av[8], xv[8];
        bf8_to_f(aggb[i], av);
        bf8_to_f(xb4[i], xv);
        float r[8];
#pragma unroll
        for (int j = 0; j < 8; ++j) {
            r[j] = xv[j] + fmaxf(av[j] * A[j] + C[j], 0.f);
            ls[j] += r[j]; lq[j] += r[j] * r[j];
        }
        y1b[i] = f_to_bf8(r);
    }
#pragma unroll
    for (int j = 0; j < 8; ++j) {
        atomicAdd(&zs[c0 + j], ls[j]);
        atomicAdd(&zq[c0 + j], lq[j]);
    }
    __syncthreads();
    int st = (blockIdx.x & (NSTRIPE - 1)) * 256;
    if (tid < 128) {
        atomicAdd(&s2[st + tid], zs[tid]);
        atomicAdd(&s2[st + 128 + tid], zq[tid]);
    }
}

// ---------------- FFN stage A: y2 = bnl(y1); hidden = relu(y2 @ W1^T + b1) ----------------
__global__ __launch_bounds__(512) void k_ffnA(const uint2* __restrict__ y1u,
                                              const float* __restrict__ s2,
                                              const float* __restrict__ g2,
                                              const float* __restrict__ bl2,
                                              const __bf16* __restrict__ W1b,
                                              const float* __restrict__ b1,
                                              uint2* __restrict__ y2u,
                                              __bf16* __restrict__ hiddenb) {
    __shared__ __bf16 ys[16 * 128];   // 4 KB, XOR-swizzled
    __shared__ __bf16 hs[16 * 256];   // 8 KB, linear
    int tid = threadIdx.x;
    int lane = tid & 63, w = tid >> 6;
    int lr = lane & 15;
    int lk = (lane >> 4) * 8;
    int lkb = lk * 2;
    int nt0 = 2 * w;

    bf16x8 B1[2][4];
    float bias1[2];
#pragma unroll
    for (int q = 0; q < 2; ++q) {
        bias1[q] = b1[(nt0 + q) * 16 + lr];
#pragma unroll
        for (int kk = 0; kk < 4; ++kk)
            B1[q][kk] = *reinterpret_cast<const bf16x8*>(&W1b[((nt0 + q) * 16 + lr) * 128 + kk * 32 + lk]);
    }

    int c0 = (tid & 31) * 4;
    int srow = tid >> 5;              // 0..15
    float A4[4], C4[4];
#pragma unroll
    for (int j = 0; j < 4; ++j) {
        int c = c0 + j;
        float m = stripe_sum(s2, c) * (1.f / NN);
        float v = stripe_sum(s2, 128 + c) * (1.f / NN) - m * m;
        float inv = rsqrtf(v + EPS_);
        A4[j] = inv * g2[c];
        C4[j] = bl2[c] - m * inv * g2[c];
    }

    for (int t = blockIdx.x; t < NTILE; t += gridDim.x) {
        size_t r0 = (size_t)t * 16;
        {
            size_t gi = ((r0 + srow) * 128 + c0) >> 2;
            uint2 u = y1u[gi];
            float f0 = bflo(u.x) * A4[0] + C4[0];
            float f1 = bfhi(u.x) * A4[1] + C4[1];
            float f2 = bflo(u.y) * A4[2] + C4[2];
            float f3 = bfhi(u.y) * A4[3] + C4[3];
            uint2 pk = make_uint2(pack_bf16x2(f0, f1), pack_bf16x2(f2, f3));
            y2u[gi] = pk;
            int sb = (srow * 256 + 2 * c0) ^ ((srow & 7) << 4);
            *reinterpret_cast<uint2*>((char*)ys + sb) = pk;
        }
        __syncthreads();

        bf16x8 Af[4];
#pragma unroll
        for (int kk = 0; kk < 4; ++kk) {
            int ab = (lr * 256 + kk * 64 + lkb) ^ ((lr & 7) << 4);
            Af[kk] = *reinterpret_cast<const bf16x8*>((char*)ys + ab);
        }
#pragma unroll
        for (int q = 0; q < 2; ++q) {
            f32x4 acc = {0.f, 0.f, 0.f, 0.f};
#pragma unroll
            for (int kk = 0; kk < 4; ++kk)
                acc = __builtin_amdgcn_mfma_f32_16x16x32_bf16(Af[kk], B1[q][kk], acc, 0, 0, 0);
            int f = (nt0 + q) * 16 + lr;
#pragma unroll
            for (int r = 0; r < 4; ++r) {
                int m = (lane >> 4) * 4 + r;
                hs[m * 256 + f] = (__bf16)fmaxf(acc[r] + bias1[q], 0.f);
            }
        }
        __syncthreads();

        {
            int hr = tid >> 5;
            int hc0 = (tid & 31) * 8;
            *reinterpret_cast<uint4*>(&hiddenb[(r0 + hr) * 256 + hc0]) =
                *reinterpret_cast<const uint4*>(&hs[hr * 256 + hc0]);
        }
        __syncthreads();   // protect ys against next iteration's stage
    }
}

// ---------------- FFN stage B: z = y2 + hidden @ W2^T + b2; striped s3 ----------------
__global__ __launch_bounds__(512) void k_ffnB(const __bf16* __restrict__ hiddenb,
                                              const uint2* __restrict__ y2u,
                                              const __bf16* __restrict__ W2b,
                                              const float* __restrict__ b2f,
                                              uint2* __restrict__ zbu,
                                              float* __restrict__ s3) {
    __shared__ __bf16 hd[16 * 256];   // 8 KB, swizzled
    __shared__ __bf16 ys2[16 * 128];  // 4 KB, linear (y2 tile)
    __shared__ float zsf[16 * 128];   // 8 KB f32 (pre-residual out)
    __shared__ float sls[128], slq[128];
    int tid = threadIdx.x;
    if (tid < 128) { sls[tid] = 0.f; slq[tid] = 0.f; }
    int lane = tid & 63, w = tid >> 6;
    int lr = lane & 15;
    int lk = (lane >> 4) * 8;
    int lkb = lk * 2;

    bf16x8 B2[8];
#pragma unroll
    for (int kk = 0; kk < 8; ++kk)
        B2[kk] = *reinterpret_cast<const bf16x8*>(&W2b[(w * 16 + lr) * 256 + kk * 32 + lk]);
    float bias2 = b2f[w * 16 + lr];

    int c0 = (tid & 31) * 4;
    int srow = tid >> 5;
    int hc0 = (tid & 31) * 8;
    float ls[4] = {0, 0, 0, 0}, lq4[4] = {0, 0, 0, 0};

    for (int t = blockIdx.x; t < NTILE; t += gridDim.x) {
        size_t r0 = (size_t)t * 16;
        {
            uint4 hu = *reinterpret_cast<const uint4*>(&hiddenb[(r0 + srow) * 256 + hc0]);
            int hb = (srow * 512 + 2 * hc0) ^ ((srow & 7) << 4);
            *reinterpret_cast<uint4*>((char*)hd + hb) = hu;
            *reinterpret_cast<uint2*>(&ys2[srow * 128 + c0]) = y2u[((r0 + srow) * 128 + c0) >> 2];
        }
        __syncthreads();

        bf16x8 Af[8];
#pragma unroll
        for (int kk = 0; kk < 8; ++kk) {
            int ab = (lr * 512 + kk * 64 + lkb) ^ ((lr & 7) << 4);
            Af[kk] = *reinterpret_cast<const bf16x8*>((char*)hd + ab);
        }
        f32x4 acc = {0.f, 0.f, 0.f, 0.f};
#pragma unroll
        for (int kk = 0; kk < 8; ++kk)
            acc = __builtin_amdgcn_mfma_f32_16x16x32_bf16(Af[kk], B2[kk], acc, 0, 0, 0);
        {
            int o = w * 16 + lr;
#pragma unroll
            for (int r = 0; r < 4; ++r) {
                int m = (lane >> 4) * 4 + r;
                zsf[m * 128 + o] = acc[r] + bias2;
            }
        }
        __syncthreads();

        {
            float4 zv = *reinterpret_cast<const float4*>(&zsf[srow * 128 + c0]);
            uint2 yv = *reinterpret_cast<const uint2*>(&ys2[srow * 128 + c0]);
            float z0 = bflo(yv.x) + zv.x;
            float z1 = bfhi(yv.x) + zv.y;
            float z2 = bflo(yv.y) + zv.z;
            float z3 = bfhi(yv.y) + zv.w;
            ls[0] += z0; lq4[0] += z0 * z0;
            ls[1] += z1; lq4[1] += z1 * z1;
            ls[2] += z2; lq4[2] += z2 * z2;
            ls[3] += z3; lq4[3] += z3 * z3;
            zbu[((r0 + srow) * 128 + c0) >> 2] = make_uint2(pack_bf16x2(z0, z1), pack_bf16x2(z2, z3));
        }
        __syncthreads();   // protect ys2/zsf against next iteration's stage
    }

    __syncthreads();
#pragma unroll
    for (int j = 0; j < 4; ++j) {
        atomicAdd(&sls[c0 + j], ls[j]);
        atomicAdd(&slq[c0 + j], lq4[j]);
    }
    __syncthreads();
    int st = (blockIdx.x & (NSTRIPE - 1)) * 256;
    if (tid < 128) {
        atomicAdd(&s3[st + tid], sls[tid]);
        atomicAdd(&s3[st + 128 + tid], slq[tid]);
    }
}

// ---------------- out = bn2(z) ----------------
__global__ __launch_bounds__(256) void k_out(const uint4* __restrict__ zb,
                                             const float* __restrict__ s3,
                                             const float* __restrict__ g,
                                             const float* __restrict__ bb,
                                             float* __restrict__ outp) {
    int tid = threadIdx.x;
    int c0 = (tid & 15) * 8;
    float A[8], C[8];
#pragma unroll
    for (int j = 0; j < 8; ++j) {
        int c = c0 + j;
        float m = stripe_sum(s3, c) * (1.f / NN);
        float v = stripe_sum(s3, 128 + c) * (1.f / NN) - m * m;
        float inv = rsqrtf(v + EPS_);
        A[j] = inv * g[c];
        C[j] = bb[c] - m * inv * g[c];
    }
    float4* o4 = (float4*)outp;
    int step = gridDim.x * 256;
    for (int i = blockIdx.x * 256 + tid; i < NN * 16; i += step) {
        float f[8];
        bf8_to_f(zb[i], f);
        float4 r0, r1;
        r0.x = f[0] * A[0] + C[0]; r0.y = f[1] * A[1] + C[1];
        r0.z = f[2] * A[2] + C[2]; r0.w = f[3] * A[3] + C[3];
        r1.x = f[4] * A[4] + C[4]; r1.y = f[5] * A[5] + C[5];
        r1.z = f[6] * A[6] + C[6]; r1.w = f[7] * A[7] + C[7];
        o4[2 * i] = r0;
        o4[2 * i + 1] = r1;
    }
}

extern "C" void kernel_launch(void* const* d_in, const int* in_sizes, int n_in,
                              void* d_out, int out_size, void* d_ws, size_t ws_size,
                              hipStream_t stream) {
    const float* x     = (const float*)d_in[0];
    const float* ea    = (const float*)d_in[1];
    const float* W     = (const float*)d_in[2];
    const float* b     = (const float*)d_in[3];
    const float* bn_g  = (const float*)d_in[4];
    const float* bn_b  = (const float*)d_in[5];
    const float* bnl_g = (const float*)d_in[6];
    const float* bnl_b = (const float*)d_in[7];
    const float* bn2_g = (const float*)d_in[8];
    const float* bn2_b = (const float*)d_in[9];
    const float* W1    = (const float*)d_in[10];
    const float* b1    = (const float*)d_in[11];
    const float* W2    = (const float*)d_in[12];
    const float* b2    = (const float*)d_in[13];
    const int*   ei    = (const int*)d_in[14];
    float* out = (float*)d_out;

    char* base = (char*)d_ws;
    __bf16* h2    = (__bf16*)base;                     // 25.6 MB (reused as z later)
    __bf16* z     = (__bf16*)base;
    int*    deg   = (int*)(base + 26000000);           // 400 KB (CSR ptr)
    int2*   pair  = (int2*)(base + 32000000);          // 12.8 MB + pad
    unsigned int* aggb = (unsigned int*)(base + 64000000);   // 25.6 MB
    uint4*        y1b  = (uint4*)(base + 96000000);          // 25.6 MB
    float* stripes = (float*)(base + 128000000);       // 48 KB
    float* s1 = stripes;
    float* s2 = stripes + NSTRIPE * 256;
    float* s3 = stripes + 2 * NSTRIPE * 256;
    int*   bsum = (int*)(base + 128100000);
    __bf16* Wb  = (__bf16*)(base + 128200000);
    __bf16* W1b = Wb + 16384;
    __bf16* W2b = W1b + 32768;
    uint2*  y2b     = (uint2*)(base + 140000000);      // 25.6 MB
    __bf16* hiddenb = (__bf16*)(base + 170000000);     // 51.2 MB
    __bf16* xb      = (__bf16*)(base + 224000000);     // 25.6 MB bf16 copy of x

    hipLaunchKernelGGL(k_init,  dim3(6250), dim3(256), 0, stream,
                       W, W1, W2, Wb, W1b, W2b, deg, stripes);
    hipLaunchKernelGGL(k_gemmx, dim3(1563), dim3(256), 0, stream, x, Wb, h2, xb);
    hipLaunchKernelGGL(k_hist,  dim3(6250), dim3(256), 0, stream, ei, deg);
    hipLaunchKernelGGL(k_scanA, dim3(98),   dim3(256), 0, stream, deg, bsum);
    hipLaunchKernelGGL(k_scanB, dim3(98),   dim3(256), 0, stream, deg, bsum, b, s1);
    hipLaunchKernelGGL(k_fill,  dim3(6250), dim3(256), 0, stream, ei, deg, pair);
    hipLaunchKernelGGL(k_gather, dim3(2048), dim3(256), 0, stream,
                       (const unsigned int*)h2, ea, (const int2*)pair, deg, b, aggb, s1);
    hipLaunchKernelGGL(k_y1,    dim3(2048), dim3(256), 0, stream,
                       (const uint4*)xb, (const uint4*)aggb, s1, bn_g, bn_b, y1b, s2);
    hipLaunchKernelGGL(k_ffnA,  dim3(512),  dim3(512), 0, stream,
                       (const uint2*)y1b, s2, bnl_g, bnl_b, W1b, b1, y2b, hiddenb);
    hipLaunchKernelGGL(k_ffnB,  dim3(512),  dim3(512), 0, stream,
                       hiddenb, (const uint2*)y2b, W2b, b2, (uint2*)z, s3);
    hipLaunchKernelGGL(k_out,   dim3(2048), dim3(256), 0, stream,
                       (const uint4*)z, s3, bn2_g, bn2_b, out);
}

// Round 18
// 584.809 us; speedup vs baseline: 1.2147x; 1.2147x over previous
//
#include <hip/hip_runtime.h>
#include <hip/hip_bf16.h>

#define NN 100000
#define NE 1600000
#define DD 128
#define FF 256
#define NSTRIPE 16
#define NTILE 6250   // NN / 16 exactly
static constexpr float EPS_ = 1e-5f;

typedef __bf16 bf16x4 __attribute__((ext_vector_type(4)));
typedef __bf16 bf16x8 __attribute__((ext_vector_type(8)));
typedef float  f32x4  __attribute__((ext_vector_type(4)));

__device__ inline float bflo(unsigned int u) { return __uint_as_float(u << 16); }
__device__ inline float bfhi(unsigned int u) { return __uint_as_float(u & 0xFFFF0000u); }

__device__ inline unsigned pack_bf16x2(float x, float y) {
    __hip_bfloat162 t;
    t.x = __float2bfloat16(x);
    t.y = __float2bfloat16(y);
    return *reinterpret_cast<unsigned*>(&t);
}
__device__ inline void bf8_to_f(uint4 u, float* f) {
    f[0] = bflo(u.x); f[1] = bfhi(u.x);
    f[2] = bflo(u.y); f[3] = bfhi(u.y);
    f[4] = bflo(u.z); f[5] = bfhi(u.z);
    f[6] = bflo(u.w); f[7] = bfhi(u.w);
}
__device__ inline uint4 f_to_bf8(const float* f) {
    uint4 u;
    u.x = pack_bf16x2(f[0], f[1]);
    u.y = pack_bf16x2(f[2], f[3]);
    u.z = pack_bf16x2(f[4], f[5]);
    u.w = pack_bf16x2(f[6], f[7]);
    return u;
}
__device__ inline float2 ntload2(const float* p) {
    double d = __builtin_nontemporal_load((const double*)p);
    return *reinterpret_cast<float2*>(&d);
}
__device__ inline float stripe_sum(const float* s, int idx) {
    float r = 0.f;
#pragma unroll
    for (int st = 0; st < NSTRIPE; ++st) r += s[st * 256 + idx];
    return r;
}

// ---------------- init: zero deg/stripes + cvt weights + aggb = bias ----------------
__global__ __launch_bounds__(256) void k_init(const float* __restrict__ W,
                                              const float* __restrict__ W1,
                                              const float* __restrict__ W2,
                                              __bf16* __restrict__ Wb,
                                              __bf16* __restrict__ W1b,
                                              __bf16* __restrict__ W2b,
                                              int* __restrict__ deg,
                                              float* __restrict__ stripes,
                                              const float* __restrict__ bias,
                                              uint4* __restrict__ aggb4) {
    int i = blockIdx.x * 256 + threadIdx.x;
    if (i < NN) deg[i] = 0;
    if (i < 3 * NSTRIPE * 256) stripes[i] = 0.f;
    if (i < 16384) Wb[i] = (__bf16)W[i];
    if (i < 32768) W1b[i] = (__bf16)W1[i];
    if (i < 32768) W2b[i] = (__bf16)W2[i];
    if (i < NN * 16) {
        int p = i & 15;
        const float4* b4 = (const float4*)bias;
        float4 u0 = b4[2 * p], u1 = b4[2 * p + 1];
        float f[8] = {u0.x, u0.y, u0.z, u0.w, u1.x, u1.y, u1.z, u1.w};
        aggb4[i] = f_to_bf8(f);
    }
}

// ---------------- h = x @ W^T -> bf16, via MFMA ----------------
__global__ __launch_bounds__(256) void k_gemmx(const float* __restrict__ x,
                                               const __bf16* __restrict__ Wb,
                                               __bf16* __restrict__ h2) {
    __shared__ __bf16 xs[64 * 128];
    int tid = threadIdx.x;
    int row0 = blockIdx.x * 64;
    int V = NN - row0; if (V > 64) V = 64;

    {
        int c0 = (tid & 31) * 4;
        for (int j = 0; j < 8; ++j) {
            int idx = j * 256 + tid;
            int r = idx >> 5;
            float4 v = make_float4(0.f, 0.f, 0.f, 0.f);
            if (r < V) v = ((const float4*)(x + (size_t)row0 * DD))[idx];
            bf16x4 bv; bv[0] = (__bf16)v.x; bv[1] = (__bf16)v.y; bv[2] = (__bf16)v.z; bv[3] = (__bf16)v.w;
            int sw = (((c0 >> 3) ^ (r & 7)) << 3) + (c0 & 7);
            *reinterpret_cast<bf16x4*>(&xs[r * 128 + sw]) = bv;
        }
    }
    __syncthreads();

    int l = tid & 63, w = tid >> 6;
    int m0 = w * 16, lr = l & 15, lk = (l >> 4) * 8;
    int mrow = m0 + lr;

    bf16x8 a[4];
    for (int kk = 0; kk < 4; ++kk) {
        int k = kk * 32 + lk;
        int sw = ((k >> 3) ^ (mrow & 7)) << 3;
        a[kk] = *reinterpret_cast<const bf16x8*>(&xs[mrow * 128 + sw]);
    }
    for (int nt = 0; nt < 8; ++nt) {
        int n0 = nt * 16;
        f32x4 acc = {0.f, 0.f, 0.f, 0.f};
        for (int kk = 0; kk < 4; ++kk) {
            bf16x8 b = *reinterpret_cast<const bf16x8*>(&Wb[(n0 + lr) * 128 + kk * 32 + lk]);
            acc = __builtin_amdgcn_mfma_f32_16x16x32_bf16(a[kk], b, acc, 0, 0, 0);
        }
        int n = n0 + lr;
#pragma unroll
        for (int r = 0; r < 4; ++r) {
            int m = m0 + (l >> 4) * 4 + r;
            xs[m * 128 + n] = (__bf16)acc[r];
        }
    }
    for (int i = 0; i < 8; ++i) {
        int j = i * 64 + l;
        int rl = j >> 5;
        int c4 = j & 31;
        int m = m0 + rl;
        if (row0 + m < NN) {
            bf16x4 v = *reinterpret_cast<const bf16x4*>(&xs[m * 128 + c4 * 4]);
            *reinterpret_cast<bf16x4*>(&h2[(size_t)(row0 + m) * 128 + c4 * 4]) = v;
        }
    }
}

// ---------------- deg histogram over dst ----------------
__global__ __launch_bounds__(256) void k_hist(const int* __restrict__ ei,
                                              int* __restrict__ deg) {
    int e = blockIdx.x * 256 + threadIdx.x;
    if (e < NE) atomicAdd(&deg[ei[NE + e]], 1);
}

// ---------------- scan stage A ----------------
__global__ __launch_bounds__(256) void k_scanA(const int* __restrict__ p,
                                               int* __restrict__ bsum) {
    __shared__ int red[256];
    int b = blockIdx.x, tid = threadIdx.x;
    int base = b * 1024;
    int s = 0;
    for (int i = tid; i < 1024; i += 256) {
        int idx = base + i;
        s += (idx < NN) ? p[idx] : 0;
    }
    red[tid] = s;
    __syncthreads();
    for (int d = 128; d > 0; d >>= 1) {
        if (tid < d) red[tid] += red[tid + d];
        __syncthreads();
    }
    if (tid == 0) bsum[b] = red[0];
}

// ---------------- scan stage B (+ empty-node stats fixup) ----------------
__global__ __launch_bounds__(256) void k_scanB(int* __restrict__ p,
                                               const int* __restrict__ bsum,
                                               const float* __restrict__ bias,
                                               float* __restrict__ s1) {
    __shared__ int part[256];
    __shared__ int boff_sh;
    int b = blockIdx.x, tid = threadIdx.x;
    if (tid == 0) {
        int s = 0;
        for (int i = 0; i < b; ++i) s += bsum[i];
        boff_sh = s;
    }
    int base = b * 1024 + tid * 4;
    int4 v = make_int4(0, 0, 0, 0);
    bool full = (base + 3 < NN);
    if (full) v = *(const int4*)(p + base);
    else {
        if (base + 0 < NN) v.x = p[base + 0];
        if (base + 1 < NN) v.y = p[base + 1];
        if (base + 2 < NN) v.z = p[base + 2];
        if (base + 3 < NN) v.w = p[base + 3];
    }
    int tsum = v.x + v.y + v.z + v.w;
    part[tid] = tsum;
    __syncthreads();
    for (int d = 1; d < 256; d <<= 1) {
        int add = (tid >= d) ? part[tid - d] : 0;
        __syncthreads();
        part[tid] += add;
        __syncthreads();
    }
    int texcl = part[tid] - tsum + boff_sh;
    int4 o;
    o.x = texcl;
    o.y = texcl + v.x;
    o.z = texcl + v.x + v.y;
    o.w = texcl + v.x + v.y + v.z;
    if (full) *(int4*)(p + base) = o;
    else {
        if (base + 0 < NN) p[base + 0] = o.x;
        if (base + 1 < NN) p[base + 1] = o.y;
        if (base + 2 < NN) p[base + 2] = o.z;
        if (base + 3 < NN) p[base + 3] = o.w;
    }
    int cnt = ((base + 0 < NN && v.x == 0) ? 1 : 0) +
              ((base + 1 < NN && v.y == 0) ? 1 : 0) +
              ((base + 2 < NN && v.z == 0) ? 1 : 0) +
              ((base + 3 < NN && v.w == 0) ? 1 : 0);
    if (cnt > 0) {
        float fc = (float)cnt;
        for (int c = 0; c < 128; ++c) {
            float bv = bias[c];
            atomicAdd(&s1[c], fc * bv);
            atomicAdd(&s1[128 + c], fc * bv * bv);
        }
    }
}

// ---------------- fill pair[pos]={src,e} sorted by dst ----------------
__global__ __launch_bounds__(256) void k_fill(const int* __restrict__ ei,
                                              int* __restrict__ ptr,
                                              int2* __restrict__ pair) {
    int e = blockIdx.x * 256 + threadIdx.x;
    if (e >= NE) return;
    int s = ei[e];
    int d = ei[NE + e];
    int pos = atomicAdd(&ptr[d], 1);
    pair[pos] = make_int2(s, e);
}

// ---------------- gather: edge-stream, readlane broadcast, 8-deep pipeline ----------------
__device__ inline int first_node_ge(const int* __restrict__ ptr, int bound) {
    if (bound <= 0) return 0;
    int a = 0, b = NN;
    while (a < b) { int m = (a + b) >> 1; if (ptr[m] >= bound) b = m; else a = m + 1; }
    return a + 1;
}

__global__ __launch_bounds__(256) void k_gather(const unsigned int* __restrict__ h2u,
                                                const float* __restrict__ ea,
                                                const int2* __restrict__ pair,
                                                const int* __restrict__ ptr,
                                                const float* __restrict__ bias,
                                                unsigned int* __restrict__ aggb,
                                                float* __restrict__ s1) {
    __shared__ float zsum[128], zsq[128];
    int tid = threadIdx.x;
    if (tid < 128) { zsum[tid] = 0.f; zsq[tid] = 0.f; }
    __syncthreads();
    int lane = tid & 63;
    int wid = blockIdx.x * 4 + (tid >> 6);
    int nw = gridDim.x * 4;
    float2 bv = ((const float2*)bias)[lane];
    float sx = 0.f, qx = 0.f, sy = 0.f, qy = 0.f;

    long long lo = (long long)wid * NE / nw;
    long long hi = (long long)(wid + 1) * NE / nw;
    int n0 = first_node_ge(ptr, (int)lo);
    int n1 = (wid == nw - 1) ? NN : first_node_ge(ptr, (int)hi);

    if (n0 < n1) {
        int jbeg = (n0 == 0) ? 0 : ptr[n0 - 1];
        int jend = ptr[n1 - 1];
        if (jbeg < jend) {
            int curn = n0;
            int cend = ptr[curn];
            while (cend == jbeg) { curn++; cend = ptr[curn]; }
            float ax = 0.f, ay = 0.f;
            int nch = (jend - jbeg + 63) >> 6;
            int2 Qc = pair[jbeg + lane];
            int2 Qn = Qc;

            unsigned H0=0,H1=0,H2=0,H3=0,H4=0,H5=0,H6=0,H7=0;
            float2 A0,A1,A2,A3,A4,A5,A6,A7;
            A0=A1=A2=A3=A4=A5=A6=A7=make_float2(0.f,0.f);

#define GISS(HS, AS, Q, SL) { \
            int sn_ = __builtin_amdgcn_readlane((Q).x, (SL)); \
            int en_ = __builtin_amdgcn_readlane((Q).y, (SL)); \
            HS = h2u[(size_t)sn_ * 64 + lane]; \
            AS = ntload2(ea + (size_t)en_ * DD + 2 * lane); }

            if (jbeg + 0 < jend) GISS(H0, A0, Qc, 0)
            if (jbeg + 1 < jend) GISS(H1, A1, Qc, 1)
            if (jbeg + 2 < jend) GISS(H2, A2, Qc, 2)
            if (jbeg + 3 < jend) GISS(H3, A3, Qc, 3)
            if (jbeg + 4 < jend) GISS(H4, A4, Qc, 4)
            if (jbeg + 5 < jend) GISS(H5, A5, Qc, 5)
            if (jbeg + 6 < jend) GISS(H6, A6, Qc, 6)
            if (jbeg + 7 < jend) GISS(H7, A7, Qc, 7)

            for (int c = 0; c < nch; ++c) {
                int cb = jbeg + (c << 6);
                if (c + 1 < nch) Qn = pair[cb + 64 + lane];
#define GSTEP(S, HS, AS) { \
                int je_ = cb + k + S; \
                if (je_ < jend) { \
                    ax += fmaxf(bflo(HS) + AS.x, 0.f); \
                    ay += fmaxf(bfhi(HS) + AS.y, 0.f); \
                    int je1_ = je_ + 1; \
                    if (je1_ == cend) { \
                        float fx_ = ax + bv.x, fy_ = ay + bv.y; \
                        aggb[(size_t)curn * 64 + lane] = pack_bf16x2(fx_, fy_); \
                        sx += fx_; qx += fx_ * fx_; sy += fy_; qy += fy_ * fy_; \
                        ax = 0.f; ay = 0.f; \
                        curn++; \
                        while (curn < n1 && ptr[curn] == je1_) curn++; \
                        cend = (curn < n1) ? ptr[curn] : -1; \
                    } \
                    int kn_ = k + S + 8; \
                    int jn_ = cb + kn_; \
                    if (jn_ < jend) { \
                        if (kn_ < 64) { GISS(HS, AS, Qc, kn_) } \
                        else { GISS(HS, AS, Qn, kn_ - 64) } \
                    } \
                } }
                for (int k = 0; k < 64; k += 8) {
                    GSTEP(0,H0,A0) GSTEP(1,H1,A1) GSTEP(2,H2,A2) GSTEP(3,H3,A3)
                    GSTEP(4,H4,A4) GSTEP(5,H5,A5) GSTEP(6,H6,A6) GSTEP(7,H7,A7)
                }
                Qc = Qn;
#undef GSTEP
            }
#undef GISS
        }
    }

    atomicAdd(&zsum[2 * lane], sx);     atomicAdd(&zsq[2 * lane], qx);
    atomicAdd(&zsum[2 * lane + 1], sy); atomicAdd(&zsq[2 * lane + 1], qy);
    __syncthreads();
    int st = (blockIdx.x & (NSTRIPE - 1)) * 256;
    if (tid < 128) {
        atomicAdd(&s1[st + tid], zsum[tid]);
        atomicAdd(&s1[st + 128 + tid], zsq[tid]);
    }
}

// ---------------- y1 = x + relu(bn1(agg)) -> bf16; striped s2 ----------------
__global__ __launch_bounds__(256) void k_y1(const float* __restrict__ x,
                                            const uint4* __restrict__ aggb,
                                            const float* __restrict__ s1,
                                            const float* __restrict__ g,
                                            const float* __restrict__ bb,
                                            uint4* __restrict__ y1b,
                                            float* __restrict__ s2) {
    __shared__ float zs[128], zq[128];
    int tid = threadIdx.x;
    if (tid < 128) { zs[tid] = 0.f; zq[tid] = 0.f; }
    __syncthreads();
    int c0 = (tid & 15) * 8;
    float A[8], C[8], ls[8] = {0,0,0,0,0,0,0,0}, lq[8] = {0,0,0,0,0,0,0,0};
#pragma unroll
    for (int j = 0; j < 8; ++j) {
        int c = c0 + j;
        float m = stripe_sum(s1, c) * (1.f / NN);
        float v = stripe_sum(s1, 128 + c) * (1.f / NN) - m * m;
        float inv = rsqrtf(v + EPS_);
        A[j] = inv * g[c];
        C[j] = bb[c] - m * inv * g[c];
    }
    int step = gridDim.x * 256;
    for (int i = blockIdx.x * 256 + tid; i < NN * 16; i += step) {
        float av[8];
        bf8_to_f(aggb[i], av);
        float4 x0 = ((const float4*)x)[2 * i];
        float4 x1 = ((const float4*)x)[2 * i + 1];
        float xv[8] = {x0.x, x0.y, x0.z, x0.w, x1.x, x1.y, x1.z, x1.w};
        float r[8];
#pragma unroll
        for (int j = 0; j < 8; ++j) {
            r[j] = xv[j] + fmaxf(av[j] * A[j] + C[j], 0.f);
            ls[j] += r[j]; lq[j] += r[j] * r[j];
        }
        y1b[i] = f_to_bf8(r);
    }
#pragma unroll
    for (int j = 0; j < 8; ++j) {
        atomicAdd(&zs[c0 + j], ls[j]);
        atomicAdd(&zq[c0 + j], lq[j]);
    }
    __syncthreads();
    int st = (blockIdx.x & (NSTRIPE - 1)) * 256;
    if (tid < 128) {
        atomicAdd(&s2[st + tid], zs[tid]);
        atomicAdd(&s2[st + 128 + tid], zq[tid]);
    }
}

// ---------------- FFN stage A: y2 = bnl(y1); hidden = relu(y2 @ W1^T + b1) ----------------
// 512 thr (8 waves), grid-stride over 16-row tiles. Wave w owns hidden cols [32w, 32w+32).
__global__ __launch_bounds__(512) void k_ffnA(const uint2* __restrict__ y1u,
                                              const float* __restrict__ s2,
                                              const float* __restrict__ g2,
                                              const float* __restrict__ bl2,
                                              const __bf16* __restrict__ W1b,
                                              const float* __restrict__ b1,
                                              uint2* __restrict__ y2u,
                                              __bf16* __restrict__ hiddenb) {
    __shared__ __bf16 ys[16 * 128];   // 4 KB, XOR-swizzled
    __shared__ __bf16 hs[16 * 256];   // 8 KB, linear
    int tid = threadIdx.x;
    int lane = tid & 63, w = tid >> 6;
    int lr = lane & 15;
    int lk = (lane >> 4) * 8;
    int lkb = lk * 2;
    int nt0 = 2 * w;

    bf16x8 B1[2][4];
    float bias1[2];
#pragma unroll
    for (int q = 0; q < 2; ++q) {
        bias1[q] = b1[(nt0 + q) * 16 + lr];
#pragma unroll
        for (int kk = 0; kk < 4; ++kk)
            B1[q][kk] = *reinterpret_cast<const bf16x8*>(&W1b[((nt0 + q) * 16 + lr) * 128 + kk * 32 + lk]);
    }

    int c0 = (tid & 31) * 4;
    int srow = tid >> 5;              // 0..15
    float A4[4], C4[4];
#pragma unroll
    for (int j = 0; j < 4; ++j) {
        int c = c0 + j;
        float m = stripe_sum(s2, c) * (1.f / NN);
        float v = stripe_sum(s2, 128 + c) * (1.f / NN) - m * m;
        float inv = rsqrtf(v + EPS_);
        A4[j] = inv * g2[c];
        C4[j] = bl2[c] - m * inv * g2[c];
    }

    for (int t = blockIdx.x; t < NTILE; t += gridDim.x) {
        size_t r0 = (size_t)t * 16;
        {
            size_t gi = ((r0 + srow) * 128 + c0) >> 2;
            uint2 u = y1u[gi];
            float f0 = bflo(u.x) * A4[0] + C4[0];
            float f1 = bfhi(u.x) * A4[1] + C4[1];
            float f2 = bflo(u.y) * A4[2] + C4[2];
            float f3 = bfhi(u.y) * A4[3] + C4[3];
            uint2 pk = make_uint2(pack_bf16x2(f0, f1), pack_bf16x2(f2, f3));
            y2u[gi] = pk;
            int sb = (srow * 256 + 2 * c0) ^ ((srow & 7) << 4);
            *reinterpret_cast<uint2*>((char*)ys + sb) = pk;
        }
        __syncthreads();

        bf16x8 Af[4];
#pragma unroll
        for (int kk = 0; kk < 4; ++kk) {
            int ab = (lr * 256 + kk * 64 + lkb) ^ ((lr & 7) << 4);
            Af[kk] = *reinterpret_cast<const bf16x8*>((char*)ys + ab);
        }
#pragma unroll
        for (int q = 0; q < 2; ++q) {
            f32x4 acc = {0.f, 0.f, 0.f, 0.f};
#pragma unroll
            for (int kk = 0; kk < 4; ++kk)
                acc = __builtin_amdgcn_mfma_f32_16x16x32_bf16(Af[kk], B1[q][kk], acc, 0, 0, 0);
            int f = (nt0 + q) * 16 + lr;
#pragma unroll
            for (int r = 0; r < 4; ++r) {
                int m = (lane >> 4) * 4 + r;
                hs[m * 256 + f] = (__bf16)fmaxf(acc[r] + bias1[q], 0.f);
            }
        }
        __syncthreads();

        {
            int hr = tid >> 5;
            int hc0 = (tid & 31) * 8;
            *reinterpret_cast<uint4*>(&hiddenb[(r0 + hr) * 256 + hc0]) =
                *reinterpret_cast<const uint4*>(&hs[hr * 256 + hc0]);
        }
        __syncthreads();   // protect ys against next iteration's stage
    }
}

// ---------------- FFN stage B: z = y2 + hidden @ W2^T + b2; striped s3 ----------------
// 512 thr (8 waves); wave w owns out cols [16w, 16w+16); W2 B-frags persistent.
__global__ __launch_bounds__(512) void k_ffnB(const __bf16* __restrict__ hiddenb,
                                              const uint2* __restrict__ y2u,
                                              const __bf16* __restrict__ W2b,
                                              const float* __restrict__ b2f,
                                              uint2* __restrict__ zbu,
                                              float* __restrict__ s3) {
    __shared__ __bf16 hd[16 * 256];   // 8 KB, swizzled
    __shared__ __bf16 ys2[16 * 128];  // 4 KB, linear (y2 tile)
    __shared__ float zsf[16 * 128];   // 8 KB f32 (pre-residual out)
    __shared__ float sls[128], slq[128];
    int tid = threadIdx.x;
    if (tid < 128) { sls[tid] = 0.f; slq[tid] = 0.f; }
    int lane = tid & 63, w = tid >> 6;
    int lr = lane & 15;
    int lk = (lane >> 4) * 8;
    int lkb = lk * 2;

    bf16x8 B2[8];
#pragma unroll
    for (int kk = 0; kk < 8; ++kk)
        B2[kk] = *reinterpret_cast<const bf16x8*>(&W2b[(w * 16 + lr) * 256 + kk * 32 + lk]);
    float bias2 = b2f[w * 16 + lr];

    int c0 = (tid & 31) * 4;
    int srow = tid >> 5;
    int hc0 = (tid & 31) * 8;
    float ls[4] = {0, 0, 0, 0}, lq4[4] = {0, 0, 0, 0};

    for (int t = blockIdx.x; t < NTILE; t += gridDim.x) {
        size_t r0 = (size_t)t * 16;
        {
            uint4 hu = *reinterpret_cast<const uint4*>(&hiddenb[(r0 + srow) * 256 + hc0]);
            int hb = (srow * 512 + 2 * hc0) ^ ((srow & 7) << 4);
            *reinterpret_cast<uint4*>((char*)hd + hb) = hu;
            *reinterpret_cast<uint2*>(&ys2[srow * 128 + c0]) = y2u[((r0 + srow) * 128 + c0) >> 2];
        }
        __syncthreads();

        bf16x8 Af[8];
#pragma unroll
        for (int kk = 0; kk < 8; ++kk) {
            int ab = (lr * 512 + kk * 64 + lkb) ^ ((lr & 7) << 4);
            Af[kk] = *reinterpret_cast<const bf16x8*>((char*)hd + ab);
        }
        f32x4 acc = {0.f, 0.f, 0.f, 0.f};
#pragma unroll
        for (int kk = 0; kk < 8; ++kk)
            acc = __builtin_amdgcn_mfma_f32_16x16x32_bf16(Af[kk], B2[kk], acc, 0, 0, 0);
        {
            int o = w * 16 + lr;
#pragma unroll
            for (int r = 0; r < 4; ++r) {
                int m = (lane >> 4) * 4 + r;
                zsf[m * 128 + o] = acc[r] + bias2;
            }
        }
        __syncthreads();

        {
            float4 zv = *reinterpret_cast<const float4*>(&zsf[srow * 128 + c0]);
            uint2 yv = *reinterpret_cast<const uint2*>(&ys2[srow * 128 + c0]);
            float z0 = bflo(yv.x) + zv.x;
            float z1 = bfhi(yv.x) + zv.y;
            float z2 = bflo(yv.y) + zv.z;
            float z3 = bfhi(yv.y) + zv.w;
            ls[0] += z0; lq4[0] += z0 * z0;
            ls[1] += z1; lq4[1] += z1 * z1;
            ls[2] += z2; lq4[2] += z2 * z2;
            ls[3] += z3; lq4[3] += z3 * z3;
            zbu[((r0 + srow) * 128 + c0) >> 2] = make_uint2(pack_bf16x2(z0, z1), pack_bf16x2(z2, z3));
        }
        __syncthreads();   // protect ys2/zsf against next iteration's stage
    }

    __syncthreads();
#pragma unroll
    for (int j = 0; j < 4; ++j) {
        atomicAdd(&sls[c0 + j], ls[j]);
        atomicAdd(&slq[c0 + j], lq4[j]);
    }
    __syncthreads();
    int st = (blockIdx.x & (NSTRIPE - 1)) * 256;
    if (tid < 128) {
        atomicAdd(&s3[st + tid], sls[tid]);
        atomicAdd(&s3[st + 128 + tid], slq[tid]);
    }
}

// ---------------- out = bn2(z) ----------------
__global__ __launch_bounds__(256) void k_out(const uint4* __restrict__ zb,
                                             const float* __restrict__ s3,
                                             const float* __restrict__ g,
                                             const float* __restrict__ bb,
                                             float* __restrict__ outp) {
    int tid = threadIdx.x;
    int c0 = (tid & 15) * 8;
    float A[8], C[8];
#pragma unroll
    for (int j = 0; j < 8; ++j) {
        int c = c0 + j;
        float m = stripe_sum(s3, c) * (1.f / NN);
        float v = stripe_sum(s3, 128 + c) * (1.f / NN) - m * m;
        float inv = rsqrtf(v + EPS_);
        A[j] = inv * g[c];
        C[j] = bb[c] - m * inv * g[c];
    }
    float4* o4 = (float4*)outp;
    int step = gridDim.x * 256;
    for (int i = blockIdx.x * 256 + tid; i < NN * 16; i += step) {
        float f[8];
        bf8_to_f(zb[i], f);
        float4 r0, r1;
        r0.x = f[0] * A[0] + C[0]; r0.y = f[1] * A[1] + C[1];
        r0.z = f[2] * A[2] + C[2]; r0.w = f[3] * A[3] + C[3];
        r1.x = f[4] * A[4] + C[4]; r1.y = f[5] * A[5] + C[5];
        r1.z = f[6] * A[6] + C[6]; r1.w = f[7] * A[7] + C[7];
        o4[2 * i] = r0;
        o4[2 * i + 1] = r1;
    }
}

extern "C" void kernel_launch(void* const* d_in, const int* in_sizes, int n_in,
                              void* d_out, int out_size, void* d_ws, size_t ws_size,
                              hipStream_t stream) {
    const float* x     = (const float*)d_in[0];
    const float* ea    = (const float*)d_in[1];
    const float* W     = (const float*)d_in[2];
    const float* b     = (const float*)d_in[3];
    const float* bn_g  = (const float*)d_in[4];
    const float* bn_b  = (const float*)d_in[5];
    const float* bnl_g = (const float*)d_in[6];
    const float* bnl_b = (const float*)d_in[7];
    const float* bn2_g = (const float*)d_in[8];
    const float* bn2_b = (const float*)d_in[9];
    const float* W1    = (const float*)d_in[10];
    const float* b1    = (const float*)d_in[11];
    const float* W2    = (const float*)d_in[12];
    const float* b2    = (const float*)d_in[13];
    const int*   ei    = (const int*)d_in[14];
    float* out = (float*)d_out;

    char* base = (char*)d_ws;
    __bf16* h2    = (__bf16*)base;                     // 25.6 MB (reused as z later)
    __bf16* z     = (__bf16*)base;
    int*    deg   = (int*)(base + 26000000);           // 400 KB (CSR ptr)
    int2*   pair  = (int2*)(base + 32000000);          // 12.8 MB + pad
    unsigned int* aggb = (unsigned int*)(base + 64000000);   // 25.6 MB
    uint4*        y1b  = (uint4*)(base + 96000000);          // 25.6 MB
    float* stripes = (float*)(base + 128000000);       // 48 KB
    float* s1 = stripes;
    float* s2 = stripes + NSTRIPE * 256;
    float* s3 = stripes + 2 * NSTRIPE * 256;
    int*   bsum = (int*)(base + 128100000);
    __bf16* Wb  = (__bf16*)(base + 128200000);
    __bf16* W1b = Wb + 16384;
    __bf16* W2b = W1b + 32768;
    uint2*  y2b     = (uint2*)(base + 140000000);      // 25.6 MB
    __bf16* hiddenb = (__bf16*)(base + 170000000);     // 51.2 MB

    hipLaunchKernelGGL(k_init,  dim3(6250), dim3(256), 0, stream,
                       W, W1, W2, Wb, W1b, W2b, deg, stripes, b, (uint4*)aggb);
    hipLaunchKernelGGL(k_gemmx, dim3(1563), dim3(256), 0, stream, x, Wb, h2);
    hipLaunchKernelGGL(k_hist,  dim3(6250), dim3(256), 0, stream, ei, deg);
    hipLaunchKernelGGL(k_scanA, dim3(98),   dim3(256), 0, stream, deg, bsum);
    hipLaunchKernelGGL(k_scanB, dim3(98),   dim3(256), 0, stream, deg, bsum, b, s1);
    hipLaunchKernelGGL(k_fill,  dim3(6250), dim3(256), 0, stream, ei, deg, pair);
    hipLaunchKernelGGL(k_gather, dim3(2048), dim3(256), 0, stream,
                       (const unsigned int*)h2, ea, (const int2*)pair, deg, b, aggb, s1);
    hipLaunchKernelGGL(k_y1,    dim3(2048), dim3(256), 0, stream,
                       x, (const uint4*)aggb, s1, bn_g, bn_b, y1b, s2);
    hipLaunchKernelGGL(k_ffnA,  dim3(512),  dim3(512), 0, stream,
                       (const uint2*)y1b, s2, bnl_g, bnl_b, W1b, b1, y2b, hiddenb);
    hipLaunchKernelGGL(k_ffnB,  dim3(512),  dim3(512), 0, stream,
                       hiddenb, (const uint2*)y2b, W2b, b2, (uint2*)z, s3);
    hipLaunchKernelGGL(k_out,   dim3(2048), dim3(256), 0, stream,
                       (const uint4*)z, s3, bn2_g, bn2_b, out);
}